// Round 1
// baseline (167.610 us; speedup 1.0000x reference)
//
#include <hip/hip_runtime.h>
#include <hip/hip_bf16.h>

// Problem constants (from reference):
#define BSZ    64
#define DLEN   65536
#define NNODES 1024
#define NFEATS 256
#define EDIM   256
#define NROWS  (BSZ * NNODES)   // 65536 (b,node) rows

// Bucketing geometry: 16 node-ranges of 64 nodes per batch.
#define NRANGE  16
#define NBUCKET (BSZ * NRANGE)  // 1024
#define LCAP    320             // per-block per-range LDS cap (mean 256, sd 15.5; overflow -> global path)
#define GCAP    4600            // per-bucket global capacity (mean 4096, sd 62 -> +8.1 sigma)
#define WPAD    268             // win row stride in words: 16B-aligned, 2-way-max LDS bank aliasing
#define HROWS   32              // rows per fused block (bucket split across 2 blocks)

typedef __bf16 bf16x8 __attribute__((ext_vector_type(8)));
typedef float  f32x4  __attribute__((ext_vector_type(4)));

// ---- bf16 helpers ----
__device__ __forceinline__ unsigned short f2bf(float x) {
  union { float f; unsigned u; } c; c.f = x;
  unsigned r = c.u + 0x7FFFu + ((c.u >> 16) & 1u);
  return (unsigned short)(r >> 16);
}

// ---- K0: convert W to bf16 + zero global bucket counters ----
__global__ __launch_bounds__(256) void wconv_kernel(
    const float* __restrict__ W, unsigned short* __restrict__ Wb,
    unsigned* __restrict__ gcnt) {
  int i = (blockIdx.x * 256 + threadIdx.x) * 4;   // 64 blocks cover 65536
  float4 w = *(const float4*)(W + i);
  ushort4 o;
  o.x = f2bf(w.x); o.y = f2bf(w.y); o.z = f2bf(w.z); o.w = f2bf(w.w);
  *(ushort4*)(Wb + i) = o;
  if (blockIdx.x == 0) ((uint4*)gcnt)[threadIdx.x] = make_uint4(0u, 0u, 0u, 0u);
}

// ---- K1: bucketize obs by (batch, node-range), LDS-staged, coalesced flush ----
// record = { pack = ((d+1)<<15)|(bf16(val)>>1),  y = (row<<16)|(row*WPAD+feat) }
// pack's unsigned max over same slot is decided by d -> last-write-wins,
// order-independent, so append order never matters.
__global__ __launch_bounds__(512, 6) void bucket_kernel(
    const float* __restrict__ x, const int* __restrict__ nid,
    const int* __restrict__ fid, unsigned* __restrict__ gcnt,
    uint2* __restrict__ gbuf) {
  __shared__ uint2 lbuf[NRANGE][LCAP];   // 40 KB
  __shared__ unsigned lcnt[NRANGE];
  __shared__ unsigned lbase[NRANGE];

  const int t = threadIdx.x;
  if (t < NRANGE) lcnt[t] = 0;
  __syncthreads();

  const int b = blockIdx.x >> 4;          // 16 blocks per batch
  const int base = blockIdx.x * 4096;

#pragma unroll
  for (int k = 0; k < 2; ++k) {
    int i = base + (k * 512 + t) * 4;     // 16B-coalesced
    float4 xv = *(const float4*)(x + i);
    int4   nv = *(const int4*)(nid + i);
    int4   fv = *(const int4*)(fid + i);
    int   nd[4] = {nv.x, nv.y, nv.z, nv.w};
    int   ft[4] = {fv.x, fv.y, fv.z, fv.w};
    float vl[4] = {xv.x, xv.y, xv.z, xv.w};
#pragma unroll
    for (int j = 0; j < 4; ++j) {
      int d = (i + j) & 0xFFFF;
      unsigned pack = (((unsigned)(d + 1)) << 15) | ((unsigned)f2bf(vl[j]) >> 1);
      int r = nd[j] >> 6;
      unsigned row = (unsigned)(nd[j] & 63);
      uint2 rec;
      rec.x = pack;
      rec.y = (row << 16) | (row * WPAD + (unsigned)ft[j]);
      unsigned li = atomicAdd(&lcnt[r], 1u);
      if (li < LCAP) {
        lbuf[r][li] = rec;
      } else {                             // rare overflow: direct global append
        unsigned gi = atomicAdd(&gcnt[b * NRANGE + r], 1u);
        if (gi < GCAP) gbuf[(size_t)(b * NRANGE + r) * GCAP + gi] = rec;
      }
    }
  }
  __syncthreads();

  if (t < NRANGE) {
    unsigned n = lcnt[t]; if (n > LCAP) n = LCAP;
    lcnt[t] = n;
    lbase[t] = atomicAdd(&gcnt[b * NRANGE + t], n);
  }
  __syncthreads();

  for (int r = 0; r < NRANGE; ++r) {
    unsigned n  = lcnt[r];
    unsigned bs = lbase[r];
    uint2* dst = gbuf + (size_t)(b * NRANGE + r) * GCAP;
    for (unsigned j = t; j < n; j += 512) {
      unsigned gi = bs + j;
      if (gi < GCAP) dst[gi] = lbuf[r][j];   // coalesced
    }
  }
}

// ---- K2: LDS window (dedup, no-return ds_max) + bf16 MFMA GEMM + epilogue ----
// Bucket q = b*16+r is split across 2 blocks (h = 0/1), each owning 32 rows:
// global rows q*64 + h*32 .. +32. Each block reads the whole bucket and
// filters by row>>5 == h. Counts recovered post-hoc by popcount scan
// (slot nonzero <=> filled, pack has d+1 in bits >=15) -- no returning
// atomics anywhere in the scatter.
// 512 threads: wave w covers cols w*32..+32. MFMA 16x16x32 bf16 mapping:
// A[m=lane&15][k=q*8+j], B[k=q*8+j][n=lane&15], D[m=q*4+reg][n=lane&15].
__global__ __launch_bounds__(512, 8) void fused_kernel(
    const unsigned* __restrict__ gcnt, const uint2* __restrict__ gbuf,
    const unsigned short* __restrict__ Wb, const float* __restrict__ bias,
    const float* __restrict__ gemb,
    float* __restrict__ out_emb, float* __restrict__ out_mask) {
  __shared__ __align__(16) unsigned win[HROWS * WPAD];  // 34.3 KB packed window
  __shared__ float scl[HROWS];

  const int t = threadIdx.x;
  const int g = blockIdx.x >> 1;      // bucket = b*16 + r
  const int h = blockIdx.x & 1;       // which 32-row half of the bucket
  const int row0 = g * 64 + h * HROWS;        // global output row base
  const int nb = (g & 15) * 64 + h * HROWS;   // node base within gemb

  // zero window
  uint4* wz = (uint4*)win;
  for (int j = t; j < (HROWS * WPAD) / 4; j += 512) wz[j] = make_uint4(0u, 0u, 0u, 0u);
  __syncthreads();

  // phase 1: dedup scatter into LDS; atomicMax result unused -> ds_max no-return
  int cn = (int)gcnt[g]; if (cn > GCAP) cn = GCAP;
  const uint2* bk = gbuf + (size_t)g * GCAP;
  const uint4* bk4 = (const uint4*)bk;
  const unsigned sub = (unsigned)(h * HROWS * WPAD);   // 0 or 8576
  int np = cn >> 1;
  for (int j = t; j < np; j += 512) {
    uint4 rr = bk4[j];                 // two records
    if (((rr.y >> 21) & 1u) == (unsigned)h) atomicMax(&win[(rr.y & 0xFFFFu) - sub], rr.x);
    if (((rr.w >> 21) & 1u) == (unsigned)h) atomicMax(&win[(rr.w & 0xFFFFu) - sub], rr.z);
  }
  if ((cn & 1) && t == 0) {
    uint2 rec = bk[cn - 1];
    if (((rec.y >> 21) & 1u) == (unsigned)h) atomicMax(&win[(rec.y & 0xFFFFu) - sub], rec.x);
  }
  __syncthreads();

  // phase 1.5: distinct counts via popcount scan. 16 threads per row; each
  // thread scans 4 of the 64 data-uint4s of its row, strided by 16 so the
  // 64 lanes of a wave land ~2-way-max on banks (row stride 67 uint4).
  {
    const int lr  = t >> 4;           // 0..31
    const int seg = t & 15;
    const uint4* rowp = (const uint4*)&win[lr * WPAD];
    int c = 0;
#pragma unroll
    for (int j = 0; j < 4; ++j) {
      uint4 w = rowp[seg + 16 * j];
      c += (w.x != 0u) + (w.y != 0u) + (w.z != 0u) + (w.w != 0u);
    }
    c += __shfl_down(c, 8, 16);
    c += __shfl_down(c, 4, 16);
    c += __shfl_down(c, 2, 16);
    c += __shfl_down(c, 1, 16);
    if (seg == 0) {
      scl[lr] = c ? 1.0f / (float)c : 0.0f;   // cnt==0 -> nan_to_num => 0
      out_mask[row0 + lr] = c ? 0.0f : 1.0f;
    }
  }

  // phase 2: MFMA GEMM. Wave w computes rows 0..31 x cols w*32..+32.
  // (win is read-only from here; no barrier needed until scl is consumed.)
  const int wv   = t >> 6;            // 0..7
  const int lane = t & 63;
  const int cl   = lane & 15;
  const int q    = lane >> 4;
  const int col0 = wv * 32;

  f32x4 acc[2][2];
#pragma unroll
  for (int mt = 0; mt < 2; ++mt)
#pragma unroll
    for (int nt = 0; nt < 2; ++nt) acc[mt][nt] = (f32x4)(0.0f);

#pragma unroll
  for (int ks = 0; ks < 8; ++ks) {
    bf16x8 bfr[2];
#pragma unroll
    for (int nt = 0; nt < 2; ++nt) {
      const uint4* wp = (const uint4*)(Wb + (size_t)(col0 + nt * 16 + cl) * NFEATS + ks * 32 + q * 8);
      bfr[nt] = __builtin_bit_cast(bf16x8, *wp);
    }
#pragma unroll
    for (int mt = 0; mt < 2; ++mt) {
      const uint4* ap = (const uint4*)&win[(mt * 16 + cl) * WPAD + ks * 32 + q * 8];
      uint4 lo = ap[0], hi = ap[1];
      uint4 pk;  // (p&0x7FFF)<<1 is the bf16 bit pattern; pack pairs little-endian
      pk.x = ((lo.x & 0x7FFFu) << 1) | ((lo.y & 0x7FFFu) << 17);
      pk.y = ((lo.z & 0x7FFFu) << 1) | ((lo.w & 0x7FFFu) << 17);
      pk.z = ((hi.x & 0x7FFFu) << 1) | ((hi.y & 0x7FFFu) << 17);
      pk.w = ((hi.z & 0x7FFFu) << 1) | ((hi.w & 0x7FFFu) << 17);
      bf16x8 afr = __builtin_bit_cast(bf16x8, pk);
#pragma unroll
      for (int nt = 0; nt < 2; ++nt)
        acc[mt][nt] = __builtin_amdgcn_mfma_f32_16x16x32_bf16(afr, bfr[nt], acc[mt][nt], 0, 0, 0);
    }
  }
  __syncthreads();   // scl visibility before epilogue

  // epilogue: out = acc/cnt + bias + gemb
#pragma unroll
  for (int nt = 0; nt < 2; ++nt) {
    int col = col0 + nt * 16 + cl;
    float bv = bias[col];
#pragma unroll
    for (int mt = 0; mt < 2; ++mt) {
#pragma unroll
      for (int r2 = 0; r2 < 4; ++r2) {
        int row = mt * 16 + q * 4 + r2;
        float o = acc[mt][nt][r2] * scl[row] + bv + gemb[(size_t)(nb + row) * EDIM + col];
        out_emb[(size_t)(row0 + row) * EDIM + col] = o;
      }
    }
  }
}

extern "C" void kernel_launch(void* const* d_in, const int* in_sizes, int n_in,
                              void* d_out, int out_size, void* d_ws, size_t ws_size,
                              hipStream_t stream) {
  const float* x    = (const float*)d_in[0];   // flat_inputs (64,65536) f32
  const int*   nid  = (const int*)d_in[1];     // node_ids    (64,65536) i32
  const int*   fid  = (const int*)d_in[2];     // feat_ids    (64,65536) i32
  const float* W    = (const float*)d_in[3];   // (256,256) f32 (embed, feat)
  const float* bias = (const float*)d_in[4];   // (256,)
  const float* gemb = (const float*)d_in[5];   // (1024,256) f32

  float* out_emb  = (float*)d_out;                   // f32 (64,1024,256)
  float* out_mask = out_emb + (size_t)NROWS * EDIM;  // f32 (64,1024,1)

  // ws layout: [gcnt 4KB (pad to 8KB)] [gbuf 1024*4600*8B = 37.7MB] [Wb 128KB]
  unsigned* gcnt = (unsigned*)d_ws;
  uint2* gbuf = (uint2*)((char*)d_ws + 8192);
  unsigned short* Wb = (unsigned short*)((char*)d_ws + 8192 + (size_t)NBUCKET * GCAP * sizeof(uint2));

  wconv_kernel<<<64, 256, 0, stream>>>(W, Wb, gcnt);
  bucket_kernel<<<(BSZ * DLEN) / 4096, 512, 0, stream>>>(x, nid, fid, gcnt, gbuf);
  fused_kernel<<<NBUCKET * 2, 512, 0, stream>>>(gcnt, gbuf, Wb, bias, gemb, out_emb, out_mask);
}

// Round 2
// 159.907 us; speedup vs baseline: 1.0482x; 1.0482x over previous
//
#include <hip/hip_runtime.h>
#include <hip/hip_bf16.h>

// Problem constants (from reference):
#define BSZ    64
#define DLEN   65536
#define NNODES 1024
#define NFEATS 256
#define EDIM   256
#define NROWS  (BSZ * NNODES)   // 65536 (b,node) rows

// Bucketing geometry: 32 node-ranges of 32 nodes per batch -> 2048 buckets.
#define NRANGE  32
#define NBUCKET (BSZ * NRANGE)  // 2048
#define CHUNK   2048            // elements per bucket_kernel block
#define LCAP    112             // per-block per-range LDS cap (mean 64, sd 7.9 -> +6 sigma; overflow -> global path)
#define GCAP    2304            // per-bucket global capacity (mean 2048, sd 45 -> +5.7 sigma)
#define WPAD    268             // win row stride in words: 16B-aligned, 2-way-max LDS bank aliasing
#define HROWS   32              // rows (nodes) per fused block == nodes per bucket

typedef __bf16 bf16x8 __attribute__((ext_vector_type(8)));
typedef float  f32x4  __attribute__((ext_vector_type(4)));

// ---- bf16 helpers ----
__device__ __forceinline__ unsigned short f2bf(float x) {
  union { float f; unsigned u; } c; c.f = x;
  unsigned r = c.u + 0x7FFFu + ((c.u >> 16) & 1u);
  return (unsigned short)(r >> 16);
}

// ---- K0: convert W to bf16 + zero global bucket counters ----
__global__ __launch_bounds__(256) void wconv_kernel(
    const float* __restrict__ W, unsigned short* __restrict__ Wb,
    unsigned* __restrict__ gcnt) {
  int i = (blockIdx.x * 256 + threadIdx.x) * 4;   // 64 blocks cover 65536
  float4 w = *(const float4*)(W + i);
  ushort4 o;
  o.x = f2bf(w.x); o.y = f2bf(w.y); o.z = f2bf(w.z); o.w = f2bf(w.w);
  *(ushort4*)(Wb + i) = o;
  if (blockIdx.x < 2)   // 2048 counters = 8 KB
    ((uint4*)gcnt)[blockIdx.x * 256 + threadIdx.x] = make_uint4(0u, 0u, 0u, 0u);
}

// ---- K1: bucketize obs by (batch, 32-node range), LDS-staged, coalesced flush ----
// record = { pack = ((d+1)<<15)|(bf16(val)>>1),  y = (nid&31)*WPAD + feat }
// pack's unsigned max over the same slot is decided by d -> last-write-wins,
// order-independent, so append order never matters.
__global__ __launch_bounds__(512, 8) void bucket_kernel(
    const float* __restrict__ x, const int* __restrict__ nid,
    const int* __restrict__ fid, unsigned* __restrict__ gcnt,
    uint2* __restrict__ gbuf) {
  __shared__ uint2 lbuf[NRANGE][LCAP];   // 28 KB
  __shared__ unsigned lcnt[NRANGE];
  __shared__ unsigned lbase[NRANGE];

  const int t = threadIdx.x;
  if (t < NRANGE) lcnt[t] = 0;
  __syncthreads();

  const int b = blockIdx.x >> 5;          // 32 blocks per batch
  const int i = blockIdx.x * CHUNK + t * 4;   // 16B-coalesced

  float4 xv = *(const float4*)(x + i);
  int4   nv = *(const int4*)(nid + i);
  int4   fv = *(const int4*)(fid + i);
  int   nd[4] = {nv.x, nv.y, nv.z, nv.w};
  int   ft[4] = {fv.x, fv.y, fv.z, fv.w};
  float vl[4] = {xv.x, xv.y, xv.z, xv.w};
#pragma unroll
  for (int j = 0; j < 4; ++j) {
    int d = (i + j) & 0xFFFF;
    unsigned pack = (((unsigned)(d + 1)) << 15) | ((unsigned)f2bf(vl[j]) >> 1);
    int r = nd[j] >> 5;
    uint2 rec;
    rec.x = pack;
    rec.y = (unsigned)((nd[j] & 31) * WPAD + ft[j]);
    unsigned li = atomicAdd(&lcnt[r], 1u);
    if (li < LCAP) {
      lbuf[r][li] = rec;
    } else {                             // rare overflow: direct global append
      unsigned gi = atomicAdd(&gcnt[b * NRANGE + r], 1u);
      if (gi < GCAP) gbuf[(size_t)(b * NRANGE + r) * GCAP + gi] = rec;
    }
  }
  __syncthreads();

  if (t < NRANGE) {
    unsigned n = lcnt[t]; if (n > LCAP) n = LCAP;
    lcnt[t] = n;
    lbase[t] = atomicAdd(&gcnt[b * NRANGE + t], n);
  }
  __syncthreads();

  // wave-parallel flush: wave wv flushes ranges wv*4 .. wv*4+3
  const int wv = t >> 6, lane = t & 63;
#pragma unroll
  for (int rr = 0; rr < 4; ++rr) {
    int r = wv * 4 + rr;
    unsigned n  = lcnt[r];
    unsigned bs = lbase[r];
    uint2* dst = gbuf + (size_t)(b * NRANGE + r) * GCAP;
    for (unsigned j = lane; j < n; j += 64) {
      unsigned gi = bs + j;
      if (gi < GCAP) dst[gi] = lbuf[r][j];   // coalesced 8B x 64
    }
  }
}

// ---- K2: LDS window (dedup, no-return ds_max) + bf16 MFMA GEMM + epilogue ----
// Block g owns bucket g: 32 nodes x 256 feats, output rows g*32..+32.
// Scatter loads are pre-issued (3 independent chunk loads in flight) before
// any LDS atomic. Distinct counts recovered post-hoc by popcount scan
// (slot nonzero <=> filled) -- no returning atomics anywhere.
// 512 threads: wave w covers cols w*32..+32. MFMA 16x16x32 bf16 mapping:
// A[m=lane&15][k=q*8+j], B[k=q*8+j][n=lane&15], D[m=q*4+reg][n=lane&15].
__global__ __launch_bounds__(512, 8) void fused_kernel(
    const unsigned* __restrict__ gcnt, const uint2* __restrict__ gbuf,
    const unsigned short* __restrict__ Wb, const float* __restrict__ bias,
    const float* __restrict__ gemb,
    float* __restrict__ out_emb, float* __restrict__ out_mask) {
  __shared__ __align__(16) unsigned win[HROWS * WPAD];  // 34.3 KB packed window
  __shared__ float scl[HROWS];

  const int t = threadIdx.x;
  const int g = blockIdx.x;                // bucket id
  const int row0 = g * HROWS;              // global output row base
  const int nb = (g & 31) * HROWS;         // node base within gemb

  // zero window
  uint4* wz = (uint4*)win;
  for (int j = t; j < (HROWS * WPAD) / 4; j += 512) wz[j] = make_uint4(0u, 0u, 0u, 0u);
  __syncthreads();

  // phase 1: dedup scatter into LDS. Pre-issue all chunk loads (np <= 1152
  // -> at most 3 chunks of 512), then do the atomics; atomicMax result
  // unused -> ds_max no-return.
  int cn = (int)gcnt[g]; if (cn > GCAP) cn = GCAP;
  const uint2* bk = gbuf + (size_t)g * GCAP;
  const uint4* bk4 = (const uint4*)bk;
  int np = cn >> 1;
  {
    uint4 r0, r1, r2;
    bool v0 = t < np, v1 = t + 512 < np, v2 = t + 1024 < np;
    if (v0) r0 = bk4[t];
    if (v1) r1 = bk4[t + 512];
    if (v2) r2 = bk4[t + 1024];
    if (v0) { atomicMax(&win[r0.y], r0.x); atomicMax(&win[r0.w], r0.z); }
    if (v1) { atomicMax(&win[r1.y], r1.x); atomicMax(&win[r1.w], r1.z); }
    if (v2) { atomicMax(&win[r2.y], r2.x); atomicMax(&win[r2.w], r2.z); }
    if ((cn & 1) && t == 0) {
      uint2 rec = bk[cn - 1];
      atomicMax(&win[rec.y], rec.x);
    }
  }
  __syncthreads();

  // phase 1.5: distinct counts via popcount scan. 16 threads per row; each
  // thread scans 4 of the 64 data-uint4s of its row, strided by 16 so the
  // 64 lanes of a wave land ~2-way-max on banks (row stride 67 uint4).
  {
    const int lr  = t >> 4;           // 0..31
    const int seg = t & 15;
    const uint4* rowp = (const uint4*)&win[lr * WPAD];
    int c = 0;
#pragma unroll
    for (int j = 0; j < 4; ++j) {
      uint4 w = rowp[seg + 16 * j];
      c += (w.x != 0u) + (w.y != 0u) + (w.z != 0u) + (w.w != 0u);
    }
    c += __shfl_down(c, 8, 16);
    c += __shfl_down(c, 4, 16);
    c += __shfl_down(c, 2, 16);
    c += __shfl_down(c, 1, 16);
    if (seg == 0) {
      scl[lr] = c ? 1.0f / (float)c : 0.0f;   // cnt==0 -> nan_to_num => 0
      out_mask[row0 + lr] = c ? 0.0f : 1.0f;
    }
  }

  // phase 2: MFMA GEMM. Wave w computes rows 0..31 x cols w*32..+32.
  // (win is read-only from here; scl consumed after the post-MFMA barrier.)
  const int wv   = t >> 6;            // 0..7
  const int lane = t & 63;
  const int cl   = lane & 15;
  const int q    = lane >> 4;
  const int col0 = wv * 32;

  f32x4 acc[2][2];
#pragma unroll
  for (int mt = 0; mt < 2; ++mt)
#pragma unroll
    for (int nt = 0; nt < 2; ++nt) acc[mt][nt] = (f32x4)(0.0f);

#pragma unroll
  for (int ks = 0; ks < 8; ++ks) {
    bf16x8 bfr[2];
#pragma unroll
    for (int nt = 0; nt < 2; ++nt) {
      const uint4* wp = (const uint4*)(Wb + (size_t)(col0 + nt * 16 + cl) * NFEATS + ks * 32 + q * 8);
      bfr[nt] = __builtin_bit_cast(bf16x8, *wp);
    }
#pragma unroll
    for (int mt = 0; mt < 2; ++mt) {
      const uint4* ap = (const uint4*)&win[(mt * 16 + cl) * WPAD + ks * 32 + q * 8];
      uint4 lo = ap[0], hi = ap[1];
      uint4 pk;  // (p&0x7FFF)<<1 is the bf16 bit pattern; pack pairs little-endian
      pk.x = ((lo.x & 0x7FFFu) << 1) | ((lo.y & 0x7FFFu) << 17);
      pk.y = ((lo.z & 0x7FFFu) << 1) | ((lo.w & 0x7FFFu) << 17);
      pk.z = ((hi.x & 0x7FFFu) << 1) | ((hi.y & 0x7FFFu) << 17);
      pk.w = ((hi.z & 0x7FFFu) << 1) | ((hi.w & 0x7FFFu) << 17);
      bf16x8 afr = __builtin_bit_cast(bf16x8, pk);
#pragma unroll
      for (int nt = 0; nt < 2; ++nt)
        acc[mt][nt] = __builtin_amdgcn_mfma_f32_16x16x32_bf16(afr, bfr[nt], acc[mt][nt], 0, 0, 0);
    }
  }
  __syncthreads();   // scl visibility before epilogue

  // epilogue: out = acc/cnt + bias + gemb
#pragma unroll
  for (int nt = 0; nt < 2; ++nt) {
    int col = col0 + nt * 16 + cl;
    float bv = bias[col];
#pragma unroll
    for (int mt = 0; mt < 2; ++mt) {
#pragma unroll
      for (int r2 = 0; r2 < 4; ++r2) {
        int row = mt * 16 + q * 4 + r2;
        float o = acc[mt][nt][r2] * scl[row] + bv + gemb[(size_t)(nb + row) * EDIM + col];
        out_emb[(size_t)(row0 + row) * EDIM + col] = o;
      }
    }
  }
}

extern "C" void kernel_launch(void* const* d_in, const int* in_sizes, int n_in,
                              void* d_out, int out_size, void* d_ws, size_t ws_size,
                              hipStream_t stream) {
  const float* x    = (const float*)d_in[0];   // flat_inputs (64,65536) f32
  const int*   nid  = (const int*)d_in[1];     // node_ids    (64,65536) i32
  const int*   fid  = (const int*)d_in[2];     // feat_ids    (64,65536) i32
  const float* W    = (const float*)d_in[3];   // (256,256) f32 (embed, feat)
  const float* bias = (const float*)d_in[4];   // (256,)
  const float* gemb = (const float*)d_in[5];   // (1024,256) f32

  float* out_emb  = (float*)d_out;                   // f32 (64,1024,256)
  float* out_mask = out_emb + (size_t)NROWS * EDIM;  // f32 (64,1024,1)

  // ws layout: [gcnt 8KB] [gbuf 2048*2304*8B = 37.75MB] [Wb 128KB]
  unsigned* gcnt = (unsigned*)d_ws;
  uint2* gbuf = (uint2*)((char*)d_ws + 8192);
  unsigned short* Wb = (unsigned short*)((char*)d_ws + 8192 + (size_t)NBUCKET * GCAP * sizeof(uint2));

  wconv_kernel<<<64, 256, 0, stream>>>(W, Wb, gcnt);
  bucket_kernel<<<(BSZ * DLEN) / CHUNK, 512, 0, stream>>>(x, nid, fid, gcnt, gbuf);
  fused_kernel<<<NBUCKET, 512, 0, stream>>>(gcnt, gbuf, Wb, bias, gemb, out_emb, out_mask);
}